// Round 4
// baseline (1149.212 us; speedup 1.0000x reference)
//
#include <hip/hip_runtime.h>
#include <hip/hip_bf16.h>

#define CDIM 256
#define MDIM 196
#define MATN (CDIM*CDIM)          // 65536
#define DTRI (CDIM*(CDIM+1)/2)    // 32896
#define PLANE 65536               // elements per bf16 plane
#define SLOT_STRIDE (2*PLANE)     // ushorts per batch per matrix slot (hi + lo plane)

typedef __attribute__((ext_vector_type(8))) short bf16x8;
typedef __attribute__((ext_vector_type(4))) float f32x4;

__device__ __constant__ int UTI[10] = {0,0,0,0,1,1,1,2,2,3};
__device__ __constant__ int UTJ[10] = {0,1,2,3,1,2,3,2,3,3};

__device__ __forceinline__ unsigned short f2bf(float f) {
    unsigned int u = __builtin_bit_cast(unsigned int, f);
    u = u + 0x7fff + ((u >> 16) & 1);           // RNE
    return (unsigned short)(u >> 16);
}
__device__ __forceinline__ float bf2f(unsigned short h) {
    unsigned int u = ((unsigned int)h) << 16;
    return __builtin_bit_cast(float, u);
}

// ---------- x -> bf16 hi/lo planes (K padded 196->256 with zeros) + row means + norm zero ----------
__global__ __launch_bounds__(256) void xcast_kernel(const float* __restrict__ x,
        unsigned short* __restrict__ xs, float* __restrict__ means, float* __restrict__ norm) {
    int b = blockIdx.y;
    int r0 = blockIdx.x * 64;
    int w = threadIdx.x >> 6, lane = threadIdx.x & 63;
    const float* xb = x + (size_t)b * CDIM * MDIM;
    unsigned short* xh = xs + (size_t)b * SLOT_STRIDE;
    unsigned short* xl = xh + PLANE;
    if (threadIdx.x == 0 && blockIdx.x == 0) norm[b] = 0.f;
    for (int k = 0; k < 16; k++) {
        int row = r0 + w * 16 + k;
        float v[4];
        float s = 0.f;
#pragma unroll
        for (int j = 0; j < 4; j++) {
            int c = j * 64 + lane;
            v[j] = (c < MDIM) ? xb[row * MDIM + c] : 0.f;
            s += v[j];
        }
#pragma unroll
        for (int off = 32; off > 0; off >>= 1) s += __shfl_down(s, off);
        if (lane == 0) means[b * CDIM + row] = s * (1.f / MDIM);
#pragma unroll
        for (int j = 0; j < 4; j++) {
            int c = j * 64 + lane;
            unsigned short h = f2bf(v[j]);
            xh[row * CDIM + c] = h;
            xl[row * CDIM + c] = f2bf(v[j] - bf2f(h));
        }
    }
}

// ---------- Ahat = A/norm (in place), Z0 = 1.5 I - 0.5 Ahat ----------
__global__ void prep_kernel(unsigned short* __restrict__ A, unsigned short* __restrict__ Z,
                            const float* __restrict__ norm, int bc) {
    int idx = blockIdx.x * 256 + threadIdx.x;   // one thread per 8 elements
    int total = bc * (MATN / 8);
    if (idx >= total) return;
    int b = idx >> 13;                          // MATN/8 = 8192
    int e0 = (idx & 8191) << 3;
    int r = e0 >> 8, c0 = e0 & 255;
    unsigned short* Ahi = A + (size_t)b * SLOT_STRIDE;
    unsigned short* Alo = Ahi + PLANE;
    unsigned short* Zhi = Z + (size_t)b * SLOT_STRIDE;
    unsigned short* Zlo = Zhi + PLANE;
    float inv = 1.f / norm[b];
    unsigned short h[8], l[8], ah[8], al[8], zh[8], zl[8];
    *(uint4*)h = *(const uint4*)&Ahi[e0];
    *(uint4*)l = *(const uint4*)&Alo[e0];
#pragma unroll
    for (int k = 0; k < 8; k++) {
        float val = (bf2f(h[k]) + bf2f(l[k])) * inv;        // Ahat element
        unsigned short hh = f2bf(val);
        ah[k] = hh; al[k] = f2bf(val - bf2f(hh));
        float z = ((r == c0 + k) ? 1.5f : 0.f) - 0.5f * val;
        unsigned short zz = f2bf(z);
        zh[k] = zz; zl[k] = f2bf(z - bf2f(zz));
    }
    *(uint4*)&Ahi[e0] = *(uint4*)ah;
    *(uint4*)&Alo[e0] = *(uint4*)al;
    *(uint4*)&Zhi[e0] = *(uint4*)zh;
    *(uint4*)&Zlo[e0] = *(uint4*)zl;
}

// ---------- unified batched MFMA GEMM on hi/lo bf16 planes, symmetric-output (upper tiles only) ----
// kind 0: D = A@B/M - mu mu^T (covariance), fused trace->atomicAdd(norm)
// kind 1: D = alpha*A@B + beta*C
// kind 2: fc epilogue: out[b0+b] += fc(triu(sqrt(norm)*(alpha*A@B + beta*C)))  (no D write)
// 1-D grid of 10*bc blocks, XCD-pinned: each batch's 10 tiles land on ONE XCD so its
// slots stay resident in that XCD's 4 MiB L2 (requires bc % 8 == 0).
__global__ __launch_bounds__(256) void bgemm_kernel(
        const unsigned short* __restrict__ Abase, const unsigned short* __restrict__ Bbase,
        const unsigned short* __restrict__ Cbase, unsigned short* __restrict__ Dbase,
        float alpha, float beta, int kind, float* __restrict__ norm,
        const float* __restrict__ means,
        const float* __restrict__ fcw, float* __restrict__ out, int b0, int bc) {
    __shared__ __align__(16) char lds[2][4][8192];   // [dbuf][Ah,Al,Bh,Bl][64 rows x 8 chunks x 16B]
    int tid = threadIdx.x;
    int lin = blockIdx.x;
    int b, tile;
    if ((bc & 7) == 0) {            // XCD-pinned mapping (blocks round-robin XCDs by lin%8)
        int xcd = lin & 7;
        int i = lin >> 3;
        int bl = i / 10;
        tile = i - bl * 10;
        b = xcd * (bc >> 3) + bl;
    } else { b = lin / 10; tile = lin - (lin / 10) * 10; }
    int ti = UTI[tile], tj = UTJ[tile];
    int r0 = ti * 64, c0 = tj * 64;

    const unsigned short* Ab = Abase + (size_t)b * SLOT_STRIDE;
    const unsigned short* Bb = Bbase + (size_t)b * SLOT_STRIDE;
    const unsigned short* srcs[4] = { Ab + (size_t)r0 * CDIM, Ab + PLANE + (size_t)r0 * CDIM,
                                      Bb + (size_t)c0 * CDIM, Bb + PLANE + (size_t)c0 * CDIM };

    int w = tid >> 6, lane = tid & 63;
    int wr = w >> 1, wc = w & 1;
    int fr = lane & 15, kq = lane >> 4;

    f32x4 acc[2][2];
#pragma unroll
    for (int i = 0; i < 2; i++)
#pragma unroll
        for (int j = 0; j < 2; j++) acc[i][j] = (f32x4){0.f, 0.f, 0.f, 0.f};

    // LDS chunk (m, c) holds logical k-window (c ^ (m&7)); dest is wave-linear so
    // global_load_lds works; the swizzle lives in the per-lane GLOBAL address.
#define STAGE(buf, k0) do {                                                              \
    _Pragma("unroll")                                                                    \
    for (int p = 0; p < 4; p++) {                                                        \
        _Pragma("unroll")                                                                \
        for (int s = 0; s < 2; s++) {                                                    \
            int cid = s * 256 + tid;                                                     \
            int m = cid >> 3;                                                            \
            int kg = (cid & 7) ^ (m & 7);                                                \
            const unsigned short* g = srcs[p] + (size_t)m * CDIM + (k0) + kg * 8;        \
            void* lp = (void*)&lds[buf][p][(s * 256 + (tid & ~63)) * 16];                \
            __builtin_amdgcn_global_load_lds(                                            \
                (const __attribute__((address_space(1))) void*)g,                        \
                (__attribute__((address_space(3))) void*)(unsigned int)(unsigned long long)lp, \
                16, 0, 0);                                                               \
        }                                                                                \
    } } while (0)

    STAGE(0, 0);
    __syncthreads();

    int cur = 0;
    for (int k0 = 0; k0 < CDIM; k0 += 64) {
        if (k0 + 64 < CDIM) STAGE(cur ^ 1, k0 + 64);
#pragma unroll
        for (int h = 0; h < 2; h++) {
            bf16x8 fAh[2], fAl[2], fBh[2], fBl[2];
#pragma unroll
            for (int i = 0; i < 2; i++) {
                int mL = wr * 32 + i * 16 + fr;
                int ca = ((h * 4 + kq) ^ (mL & 7));
                fAh[i] = *(const bf16x8*)&lds[cur][0][(mL * 8 + ca) * 16];
                fAl[i] = *(const bf16x8*)&lds[cur][1][(mL * 8 + ca) * 16];
                int nL = wc * 32 + i * 16 + fr;
                int cb = ((h * 4 + kq) ^ (nL & 7));
                fBh[i] = *(const bf16x8*)&lds[cur][2][(nL * 8 + cb) * 16];
                fBl[i] = *(const bf16x8*)&lds[cur][3][(nL * 8 + cb) * 16];
            }
#pragma unroll
            for (int i = 0; i < 2; i++)
#pragma unroll
                for (int j = 0; j < 2; j++) {
                    acc[i][j] = __builtin_amdgcn_mfma_f32_16x16x32_bf16(fAh[i], fBh[j], acc[i][j], 0, 0, 0);
                    acc[i][j] = __builtin_amdgcn_mfma_f32_16x16x32_bf16(fAh[i], fBl[j], acc[i][j], 0, 0, 0);
                    acc[i][j] = __builtin_amdgcn_mfma_f32_16x16x32_bf16(fAl[i], fBh[j], acc[i][j], 0, 0, 0);
                }
        }
        __syncthreads();
        cur ^= 1;
    }

    const unsigned short* Chi = Cbase ? Cbase + (size_t)b * SLOT_STRIDE : nullptr;
    const unsigned short* Clo = Chi ? Chi + PLANE : nullptr;

    if (kind == 2) {
        float s = sqrtf(norm[b]);
        float s0 = 0.f, s1 = 0.f;
#pragma unroll
        for (int i = 0; i < 2; i++)
#pragma unroll
            for (int j = 0; j < 2; j++)
#pragma unroll
                for (int rr = 0; rr < 4; rr++) {
                    int row = r0 + wr * 32 + i * 16 + kq * 4 + rr;
                    int col = c0 + wc * 32 + j * 16 + fr;
                    float v = alpha * acc[i][j][rr];
                    if (Chi) v += beta * (bf2f(Chi[row * CDIM + col]) + bf2f(Clo[row * CDIM + col]));
                    v *= s;
                    if (col >= row) {
                        int t = row * CDIM - (row * (row - 1)) / 2 + (col - row);
                        s0 = fmaf(v, fcw[t], s0);
                        s1 = fmaf(v, fcw[DTRI + t], s1);
                    }
                }
#pragma unroll
        for (int off = 32; off > 0; off >>= 1) { s0 += __shfl_down(s0, off); s1 += __shfl_down(s1, off); }
        __syncthreads();
        float* red = (float*)&lds[0][0][0];
        if (lane == 0) { red[w * 2] = s0; red[w * 2 + 1] = s1; }
        __syncthreads();
        if (tid == 0) {
            atomicAdd(&out[(size_t)(b0 + b) * 2 + 0], red[0] + red[2] + red[4] + red[6]);
            atomicAdd(&out[(size_t)(b0 + b) * 2 + 1], red[1] + red[3] + red[5] + red[7]);
        }
        return;
    }

    // kind 0/1: compute values, direct write, then mirrored write for off-diagonal tiles
    float vv[2][2][4];
    if (kind == 0) {
        const float* mub = means + b * CDIM;
        float tsum = 0.f;
#pragma unroll
        for (int i = 0; i < 2; i++)
#pragma unroll
            for (int j = 0; j < 2; j++)
#pragma unroll
                for (int rr = 0; rr < 4; rr++) {
                    int row = r0 + wr * 32 + i * 16 + kq * 4 + rr;
                    int col = c0 + wc * 32 + j * 16 + fr;
                    float v = acc[i][j][rr] * (1.f / MDIM) - mub[row] * mub[col];
                    vv[i][j][rr] = v;
                    if (row == col) tsum += v;
                }
        if (ti == tj && wr == wc) {              // fused trace: wave-reduce, then 1 atomic/wave
#pragma unroll
            for (int off = 32; off > 0; off >>= 1) tsum += __shfl_down(tsum, off);
            if (lane == 0) atomicAdd(&norm[b], tsum);
        }
    } else {
#pragma unroll
        for (int i = 0; i < 2; i++)
#pragma unroll
            for (int j = 0; j < 2; j++)
#pragma unroll
                for (int rr = 0; rr < 4; rr++) {
                    int row = r0 + wr * 32 + i * 16 + kq * 4 + rr;
                    int col = c0 + wc * 32 + j * 16 + fr;
                    float v = alpha * acc[i][j][rr];
                    if (Chi) v += beta * (bf2f(Chi[row * CDIM + col]) + bf2f(Clo[row * CDIM + col]));
                    vv[i][j][rr] = v;
                }
    }

    unsigned short* Dhi = Dbase + (size_t)b * SLOT_STRIDE;
    unsigned short* Dlo = Dhi + PLANE;
#pragma unroll
    for (int i = 0; i < 2; i++)
#pragma unroll
        for (int j = 0; j < 2; j++)
#pragma unroll
            for (int rr = 0; rr < 4; rr++) {
                int row = r0 + wr * 32 + i * 16 + kq * 4 + rr;
                int col = c0 + wc * 32 + j * 16 + fr;
                float v = vv[i][j][rr];
                unsigned short hh = f2bf(v);
                Dhi[row * CDIM + col] = hh;
                Dlo[row * CDIM + col] = f2bf(v - bf2f(hh));
            }

    if (ti != tj) {                              // mirrored block via padded LDS transpose
        float* T = (float*)&lds[0][0][0];        // [64][68] floats = 17408 B
#pragma unroll
        for (int i = 0; i < 2; i++)
#pragma unroll
            for (int j = 0; j < 2; j++)
#pragma unroll
                for (int rr = 0; rr < 4; rr++) {
                    int rl = wr * 32 + i * 16 + kq * 4 + rr;
                    int cl = wc * 32 + j * 16 + fr;
                    T[cl * 68 + rl] = vv[i][j][rr];
                }
        __syncthreads();
#pragma unroll
        for (int t = 0; t < 16; t++) {
            int idx = t * 256 + tid;
            int rr_ = idx >> 6;                  // local col index -> mirrored row
            int cc_ = idx & 63;                  // local row index -> mirrored col
            float v = T[rr_ * 68 + cc_];
            unsigned short hh = f2bf(v);
            Dhi[(c0 + rr_) * CDIM + (r0 + cc_)] = hh;
            Dlo[(c0 + rr_) * CDIM + (r0 + cc_)] = f2bf(v - bf2f(hh));
        }
    }
#undef STAGE
}

// ---------- out init with bias ----------
__global__ void init_out(float* __restrict__ out, const float* __restrict__ bias, int n) {
    int i = blockIdx.x * 256 + threadIdx.x;
    if (i < n) out[i] = bias[i & 1];
}

extern "C" void kernel_launch(void* const* d_in, const int* in_sizes, int n_in,
                              void* d_out, int out_size, void* d_ws, size_t ws_size,
                              hipStream_t stream) {
    const float* x    = (const float*)d_in[0];
    const float* fc_w = (const float*)d_in[1];
    const float* fc_b = (const float*)d_in[2];
    float* out = (float*)d_out;
    int B = in_sizes[0] / (CDIM * MDIM);

    size_t per_b = (size_t)4 * SLOT_STRIDE * sizeof(unsigned short)
                 + (size_t)CDIM * sizeof(float) + sizeof(float);
    int Bcmax = (int)(ws_size / per_b);
    if (Bcmax < 1) Bcmax = 1;
    if (Bcmax > B) Bcmax = B;
    // Cap at 32: 4 slots x 32 batches = 32 MiB = aggregate L2; with XCD-pinned
    // mapping each XCD holds 4 batches x 1 MiB = its full 4 MiB L2.
    int Bc = Bcmax > 32 ? 32 : Bcmax;
    if (Bc >= 8) Bc &= ~7;

    char* p = (char*)d_ws;
    unsigned short* slot[4];
    for (int i = 0; i < 4; i++) { slot[i] = (unsigned short*)p; p += (size_t)Bc * SLOT_STRIDE * sizeof(unsigned short); }
    float* means = (float*)p; p += (size_t)Bc * CDIM * sizeof(float);
    float* norm  = (float*)p;

    init_out<<<(out_size + 255) / 256, 256, 0, stream>>>(out, fc_b, out_size);

    for (int b0 = 0; b0 < B; b0 += Bc) {
        int bc = (Bc < B - b0) ? Bc : (B - b0);
        const float* xb = x + (size_t)b0 * CDIM * MDIM;

        unsigned short* A  = slot[0];
        unsigned short* z  = slot[1];
        unsigned short* t1 = slot[2];
        unsigned short* t2 = slot[3];

        // x -> bf16 planes in t2 (dead until GEMM2), + means + norm=0
        xcast_kernel<<<dim3(4, bc), 256, 0, stream>>>(xb, t2, means, norm);
        // covariance via MFMA (A=B=x planes), fused trace
        bgemm_kernel<<<10 * bc, 256, 0, stream>>>(t2, t2, nullptr, A, 0.f, 0.f, 0, norm, means, nullptr, nullptr, b0, bc);
        // Ahat in place + Z0
        prep_kernel<<<bc * 32, 256, 0, stream>>>(A, z, norm, bc);

        int g = 10 * bc;
        for (int it = 0; it < 3; it++) {
            bgemm_kernel<<<g, 256, 0, stream>>>(A,  z,  nullptr, t1, 1.f,  0.f, 1, norm, means, nullptr, nullptr, b0, bc); // t1 = Ahat@z
            bgemm_kernel<<<g, 256, 0, stream>>>(z,  t1, nullptr, t2, 1.f,  0.f, 1, norm, means, nullptr, nullptr, b0, bc); // t2 = z@t1
            bgemm_kernel<<<g, 256, 0, stream>>>(t2, z,  z,       t1, -0.5f, 1.5f, 1, norm, means, nullptr, nullptr, b0, bc); // z' = 1.5z-0.5 t2@z
            unsigned short* tmp = z; z = t1; t1 = tmp;
        }
        bgemm_kernel<<<g, 256, 0, stream>>>(A, z,  nullptr, t1, 1.f,  0.f, 1, norm, means, nullptr, nullptr, b0, bc);      // Y3 = Ahat@z
        bgemm_kernel<<<g, 256, 0, stream>>>(z, t1, nullptr, t2, 1.f,  0.f, 1, norm, means, nullptr, nullptr, b0, bc);      // P  = z@Y3
        bgemm_kernel<<<g, 256, 0, stream>>>(t1, t2, t1, nullptr, -0.5f, 1.5f, 2, norm, means, fc_w, out, b0, bc);          // fc epilogue
    }
}

// Round 5
// 1097.330 us; speedup vs baseline: 1.0473x; 1.0473x over previous
//
#include <hip/hip_runtime.h>
#include <hip/hip_bf16.h>

#define CDIM 256
#define MDIM 196
#define MATN (CDIM*CDIM)          // 65536
#define DTRI (CDIM*(CDIM+1)/2)    // 32896
#define PLANE 65536               // elements per bf16 plane
#define SLOT_STRIDE (2*PLANE)     // ushorts per batch per matrix slot (hi + lo plane)

typedef __attribute__((ext_vector_type(8))) short bf16x8;
typedef __attribute__((ext_vector_type(4))) float f32x4;

__device__ __forceinline__ unsigned short f2bf(float f) {
    unsigned int u = __builtin_bit_cast(unsigned int, f);
    u = u + 0x7fff + ((u >> 16) & 1);           // RNE
    return (unsigned short)(u >> 16);
}
__device__ __forceinline__ float bf2f(unsigned short h) {
    unsigned int u = ((unsigned int)h) << 16;
    return __builtin_bit_cast(float, u);
}

// ---------- x -> bf16 hi/lo planes (K padded 196->256 with zeros) + row means + norm zero ----------
__global__ __launch_bounds__(256) void xcast_kernel(const float* __restrict__ x,
        unsigned short* __restrict__ xs, float* __restrict__ means, float* __restrict__ norm) {
    int b = blockIdx.y;
    int r0 = blockIdx.x * 64;
    int w = threadIdx.x >> 6, lane = threadIdx.x & 63;
    const float* xb = x + (size_t)b * CDIM * MDIM;
    unsigned short* xh = xs + (size_t)b * SLOT_STRIDE;
    unsigned short* xl = xh + PLANE;
    if (threadIdx.x == 0 && blockIdx.x == 0) norm[b] = 0.f;
    for (int k = 0; k < 16; k++) {
        int row = r0 + w * 16 + k;
        float v[4];
        float s = 0.f;
#pragma unroll
        for (int j = 0; j < 4; j++) {
            int c = j * 64 + lane;
            v[j] = (c < MDIM) ? xb[row * MDIM + c] : 0.f;
            s += v[j];
        }
#pragma unroll
        for (int off = 32; off > 0; off >>= 1) s += __shfl_down(s, off);
        if (lane == 0) means[b * CDIM + row] = s * (1.f / MDIM);
#pragma unroll
        for (int j = 0; j < 4; j++) {
            int c = j * 64 + lane;
            unsigned short h = f2bf(v[j]);
            xh[row * CDIM + c] = h;
            xl[row * CDIM + c] = f2bf(v[j] - bf2f(h));
        }
    }
}

// ---------- Ahat = A/norm (in place), Z0 = 1.5 I - 0.5 Ahat ----------
__global__ void prep_kernel(unsigned short* __restrict__ A, unsigned short* __restrict__ Z,
                            const float* __restrict__ norm, int bc) {
    int idx = blockIdx.x * 256 + threadIdx.x;   // one thread per 8 elements
    int total = bc * (MATN / 8);
    if (idx >= total) return;
    int b = idx >> 13;                          // MATN/8 = 8192
    int e0 = (idx & 8191) << 3;
    int r = e0 >> 8, c0 = e0 & 255;
    unsigned short* Ahi = A + (size_t)b * SLOT_STRIDE;
    unsigned short* Alo = Ahi + PLANE;
    unsigned short* Zhi = Z + (size_t)b * SLOT_STRIDE;
    unsigned short* Zlo = Zhi + PLANE;
    float inv = 1.f / norm[b];
    unsigned short h[8], l[8], ah[8], al[8], zh[8], zl[8];
    *(uint4*)h = *(const uint4*)&Ahi[e0];
    *(uint4*)l = *(const uint4*)&Alo[e0];
#pragma unroll
    for (int k = 0; k < 8; k++) {
        float val = (bf2f(h[k]) + bf2f(l[k])) * inv;        // Ahat element
        unsigned short hh = f2bf(val);
        ah[k] = hh; al[k] = f2bf(val - bf2f(hh));
        float z = ((r == c0 + k) ? 1.5f : 0.f) - 0.5f * val;
        unsigned short zz = f2bf(z);
        zh[k] = zz; zl[k] = f2bf(z - bf2f(zz));
    }
    *(uint4*)&Ahi[e0] = *(uint4*)ah;
    *(uint4*)&Alo[e0] = *(uint4*)al;
    *(uint4*)&Zhi[e0] = *(uint4*)zh;
    *(uint4*)&Zlo[e0] = *(uint4*)zl;
}

// ---------- unified batched MFMA GEMM on hi/lo bf16 planes (full 16-tile output) ----------
// kind 0: D = A@B/M - mu mu^T (covariance), fused trace->atomicAdd(norm)
// kind 1: D = alpha*A@B + beta*C
// kind 2: fc epilogue: out[b0+b] += fc(triu(sqrt(norm)*(alpha*A@B + beta*C)))  (no D write)
// 1-D grid of 16*bc blocks, XCD-pinned: each batch's 16 tiles land on ONE XCD so its
// 4 slots (1 MiB) x 4 batches stay resident in that XCD's 4 MiB L2 (requires bc % 8 == 0).
// B-operand read row-major relying on symmetry (all NS iterates are symmetric; for
// covariance B == A == x so B[k][n] fragment = x[n][k] row read, also correct).
__global__ __launch_bounds__(256) void bgemm_kernel(
        const unsigned short* __restrict__ Abase, const unsigned short* __restrict__ Bbase,
        const unsigned short* __restrict__ Cbase, unsigned short* __restrict__ Dbase,
        float alpha, float beta, int kind, float* __restrict__ norm,
        const float* __restrict__ means,
        const float* __restrict__ fcw, float* __restrict__ out, int b0, int bc) {
    __shared__ __align__(16) char lds[2][4][8192];   // [dbuf][Ah,Al,Bh,Bl][64 rows x 8 chunks x 16B]
    int tid = threadIdx.x;
    int lin = blockIdx.x;
    int b, tile;
    if ((bc & 7) == 0) {            // XCD-pinned mapping (blocks round-robin XCDs by lin%8)
        int xcd = lin & 7;
        int i = lin >> 3;
        b = xcd * (bc >> 3) + (i >> 4);
        tile = i & 15;
    } else { b = lin >> 4; tile = lin & 15; }
    int r0 = (tile >> 2) * 64, c0 = (tile & 3) * 64;

    const unsigned short* Ab = Abase + (size_t)b * SLOT_STRIDE;
    const unsigned short* Bb = Bbase + (size_t)b * SLOT_STRIDE;
    const unsigned short* srcs[4] = { Ab + (size_t)r0 * CDIM, Ab + PLANE + (size_t)r0 * CDIM,
                                      Bb + (size_t)c0 * CDIM, Bb + PLANE + (size_t)c0 * CDIM };

    int w = tid >> 6, lane = tid & 63;
    int wr = w >> 1, wc = w & 1;
    int fr = lane & 15, kq = lane >> 4;

    f32x4 acc[2][2];
#pragma unroll
    for (int i = 0; i < 2; i++)
#pragma unroll
        for (int j = 0; j < 2; j++) acc[i][j] = (f32x4){0.f, 0.f, 0.f, 0.f};

    // LDS chunk (m, c) holds logical k-window (c ^ (m&7)); dest is wave-linear so
    // global_load_lds works; the swizzle lives in the per-lane GLOBAL address.
#define STAGE(buf, k0) do {                                                              \
    _Pragma("unroll")                                                                    \
    for (int p = 0; p < 4; p++) {                                                        \
        _Pragma("unroll")                                                                \
        for (int s = 0; s < 2; s++) {                                                    \
            int cid = s * 256 + tid;                                                     \
            int m = cid >> 3;                                                            \
            int kg = (cid & 7) ^ (m & 7);                                                \
            const unsigned short* g = srcs[p] + (size_t)m * CDIM + (k0) + kg * 8;        \
            void* lp = (void*)&lds[buf][p][(s * 256 + (tid & ~63)) * 16];                \
            __builtin_amdgcn_global_load_lds(                                            \
                (const __attribute__((address_space(1))) void*)g,                        \
                (__attribute__((address_space(3))) void*)(unsigned int)(unsigned long long)lp, \
                16, 0, 0);                                                               \
        }                                                                                \
    } } while (0)

    STAGE(0, 0);
    __syncthreads();

    int cur = 0;
    for (int k0 = 0; k0 < CDIM; k0 += 64) {
        if (k0 + 64 < CDIM) STAGE(cur ^ 1, k0 + 64);
#pragma unroll
        for (int h = 0; h < 2; h++) {
            bf16x8 fAh[2], fAl[2], fBh[2], fBl[2];
#pragma unroll
            for (int i = 0; i < 2; i++) {
                int mL = wr * 32 + i * 16 + fr;
                int ca = ((h * 4 + kq) ^ (mL & 7));
                fAh[i] = *(const bf16x8*)&lds[cur][0][(mL * 8 + ca) * 16];
                fAl[i] = *(const bf16x8*)&lds[cur][1][(mL * 8 + ca) * 16];
                int nL = wc * 32 + i * 16 + fr;
                int cb = ((h * 4 + kq) ^ (nL & 7));
                fBh[i] = *(const bf16x8*)&lds[cur][2][(nL * 8 + cb) * 16];
                fBl[i] = *(const bf16x8*)&lds[cur][3][(nL * 8 + cb) * 16];
            }
#pragma unroll
            for (int i = 0; i < 2; i++)
#pragma unroll
                for (int j = 0; j < 2; j++) {
                    acc[i][j] = __builtin_amdgcn_mfma_f32_16x16x32_bf16(fAh[i], fBh[j], acc[i][j], 0, 0, 0);
                    acc[i][j] = __builtin_amdgcn_mfma_f32_16x16x32_bf16(fAh[i], fBl[j], acc[i][j], 0, 0, 0);
                    acc[i][j] = __builtin_amdgcn_mfma_f32_16x16x32_bf16(fAl[i], fBh[j], acc[i][j], 0, 0, 0);
                }
        }
        __syncthreads();
        cur ^= 1;
    }

    const unsigned short* Chi = Cbase ? Cbase + (size_t)b * SLOT_STRIDE : nullptr;
    const unsigned short* Clo = Chi ? Chi + PLANE : nullptr;

    if (kind == 2) {
        float s = sqrtf(norm[b]);
        float s0 = 0.f, s1 = 0.f;
#pragma unroll
        for (int i = 0; i < 2; i++)
#pragma unroll
            for (int j = 0; j < 2; j++)
#pragma unroll
                for (int rr = 0; rr < 4; rr++) {
                    int row = r0 + wr * 32 + i * 16 + kq * 4 + rr;
                    int col = c0 + wc * 32 + j * 16 + fr;
                    float v = alpha * acc[i][j][rr];
                    if (Chi) v += beta * (bf2f(Chi[row * CDIM + col]) + bf2f(Clo[row * CDIM + col]));
                    v *= s;
                    if (col >= row) {
                        int t = row * CDIM - (row * (row - 1)) / 2 + (col - row);
                        s0 = fmaf(v, fcw[t], s0);
                        s1 = fmaf(v, fcw[DTRI + t], s1);
                    }
                }
#pragma unroll
        for (int off = 32; off > 0; off >>= 1) { s0 += __shfl_down(s0, off); s1 += __shfl_down(s1, off); }
        __syncthreads();
        float* red = (float*)&lds[0][0][0];
        if (lane == 0) { red[w * 2] = s0; red[w * 2 + 1] = s1; }
        __syncthreads();
        if (tid == 0) {
            atomicAdd(&out[(size_t)(b0 + b) * 2 + 0], red[0] + red[2] + red[4] + red[6]);
            atomicAdd(&out[(size_t)(b0 + b) * 2 + 1], red[1] + red[3] + red[5] + red[7]);
        }
        return;
    }

    unsigned short* Dhi = Dbase + (size_t)b * SLOT_STRIDE;
    unsigned short* Dlo = Dhi + PLANE;

    if (kind == 0) {
        const float* mub = means + b * CDIM;
        float tsum = 0.f;
#pragma unroll
        for (int i = 0; i < 2; i++)
#pragma unroll
            for (int j = 0; j < 2; j++)
#pragma unroll
                for (int rr = 0; rr < 4; rr++) {
                    int row = r0 + wr * 32 + i * 16 + kq * 4 + rr;
                    int col = c0 + wc * 32 + j * 16 + fr;
                    float v = acc[i][j][rr] * (1.f / MDIM) - mub[row] * mub[col];
                    if (row == col) tsum += v;
                    unsigned short hh = f2bf(v);
                    Dhi[row * CDIM + col] = hh;
                    Dlo[row * CDIM + col] = f2bf(v - bf2f(hh));
                }
        if (r0 == c0 && wr == wc) {              // fused trace: wave-reduce, 1 atomic/wave
#pragma unroll
            for (int off = 32; off > 0; off >>= 1) tsum += __shfl_down(tsum, off);
            if (lane == 0) atomicAdd(&norm[b], tsum);
        }
    } else {
#pragma unroll
        for (int i = 0; i < 2; i++)
#pragma unroll
            for (int j = 0; j < 2; j++)
#pragma unroll
                for (int rr = 0; rr < 4; rr++) {
                    int row = r0 + wr * 32 + i * 16 + kq * 4 + rr;
                    int col = c0 + wc * 32 + j * 16 + fr;
                    float v = alpha * acc[i][j][rr];
                    if (Chi) v += beta * (bf2f(Chi[row * CDIM + col]) + bf2f(Clo[row * CDIM + col]));
                    unsigned short hh = f2bf(v);
                    Dhi[row * CDIM + col] = hh;
                    Dlo[row * CDIM + col] = f2bf(v - bf2f(hh));
                }
    }
#undef STAGE
}

// ---------- out init with bias ----------
__global__ void init_out(float* __restrict__ out, const float* __restrict__ bias, int n) {
    int i = blockIdx.x * 256 + threadIdx.x;
    if (i < n) out[i] = bias[i & 1];
}

extern "C" void kernel_launch(void* const* d_in, const int* in_sizes, int n_in,
                              void* d_out, int out_size, void* d_ws, size_t ws_size,
                              hipStream_t stream) {
    const float* x    = (const float*)d_in[0];
    const float* fc_w = (const float*)d_in[1];
    const float* fc_b = (const float*)d_in[2];
    float* out = (float*)d_out;
    int B = in_sizes[0] / (CDIM * MDIM);

    size_t per_b = (size_t)4 * SLOT_STRIDE * sizeof(unsigned short)
                 + (size_t)CDIM * sizeof(float) + sizeof(float);
    int Bcmax = (int)(ws_size / per_b);
    if (Bcmax < 1) Bcmax = 1;
    if (Bcmax > B) Bcmax = B;
    // Cap at 32: with XCD-pinned mapping each XCD holds 4 batches x 1 MiB (4 slots)
    // = its full 4 MiB L2 -> GEMM chain stays L2-resident (R2: 0 conflicts, ~3.4us).
    int Bc = Bcmax > 32 ? 32 : Bcmax;
    if (Bc >= 8) Bc &= ~7;

    char* p = (char*)d_ws;
    unsigned short* slot[4];
    for (int i = 0; i < 4; i++) { slot[i] = (unsigned short*)p; p += (size_t)Bc * SLOT_STRIDE * sizeof(unsigned short); }
    float* means = (float*)p; p += (size_t)Bc * CDIM * sizeof(float);
    float* norm  = (float*)p;

    init_out<<<(out_size + 255) / 256, 256, 0, stream>>>(out, fc_b, out_size);

    for (int b0 = 0; b0 < B; b0 += Bc) {
        int bc = (Bc < B - b0) ? Bc : (B - b0);
        const float* xb = x + (size_t)b0 * CDIM * MDIM;

        unsigned short* A  = slot[0];
        unsigned short* z  = slot[1];
        unsigned short* t1 = slot[2];
        unsigned short* t2 = slot[3];

        // x -> bf16 planes in t2 (dead until GEMM2), + means + norm=0
        xcast_kernel<<<dim3(4, bc), 256, 0, stream>>>(xb, t2, means, norm);
        // covariance via MFMA (A=B=x planes), fused trace
        bgemm_kernel<<<16 * bc, 256, 0, stream>>>(t2, t2, nullptr, A, 0.f, 0.f, 0, norm, means, nullptr, nullptr, b0, bc);
        // Ahat in place + Z0
        prep_kernel<<<bc * 32, 256, 0, stream>>>(A, z, norm, bc);

        int g = 16 * bc;
        for (int it = 0; it < 3; it++) {
            bgemm_kernel<<<g, 256, 0, stream>>>(A,  z,  nullptr, t1, 1.f,  0.f, 1, norm, means, nullptr, nullptr, b0, bc); // t1 = Ahat@z
            bgemm_kernel<<<g, 256, 0, stream>>>(z,  t1, nullptr, t2, 1.f,  0.f, 1, norm, means, nullptr, nullptr, b0, bc); // t2 = z@t1
            bgemm_kernel<<<g, 256, 0, stream>>>(t2, z,  z,       t1, -0.5f, 1.5f, 1, norm, means, nullptr, nullptr, b0, bc); // z' = 1.5z-0.5 t2@z
            unsigned short* tmp = z; z = t1; t1 = tmp;
        }
        bgemm_kernel<<<g, 256, 0, stream>>>(A, z,  nullptr, t1, 1.f,  0.f, 1, norm, means, nullptr, nullptr, b0, bc);      // Y3 = Ahat@z
        bgemm_kernel<<<g, 256, 0, stream>>>(z, t1, nullptr, t2, 1.f,  0.f, 1, norm, means, nullptr, nullptr, b0, bc);      // P  = z@Y3
        bgemm_kernel<<<g, 256, 0, stream>>>(t1, t2, t1, nullptr, -0.5f, 1.5f, 2, norm, means, fc_w, out, b0, bc);          // fc epilogue
    }
}

// Round 7
// 795.119 us; speedup vs baseline: 1.4453x; 1.3801x over previous
//
#include <hip/hip_runtime.h>
#include <hip/hip_bf16.h>

#define CDIM 256
#define MDIM 196
#define MATN (CDIM*CDIM)          // 65536
#define DTRI (CDIM*(CDIM+1)/2)    // 32896
#define PLANE 65536               // elements per bf16 plane
#define SLOT_STRIDE (2*PLANE)     // ushorts per batch per matrix slot (hi + lo plane)

typedef __attribute__((ext_vector_type(8))) short bf16x8;
typedef __attribute__((ext_vector_type(4))) float f32x4;

__device__ __forceinline__ unsigned short f2bf(float f) {
    unsigned int u = __builtin_bit_cast(unsigned int, f);
    u = u + 0x7fff + ((u >> 16) & 1);           // RNE
    return (unsigned short)(u >> 16);
}
__device__ __forceinline__ float bf2f(unsigned short h) {
    unsigned int u = ((unsigned int)h) << 16;
    return __builtin_bit_cast(float, u);
}

// ---------- x -> bf16 hi/lo planes (K padded 196->256 with zeros) + row means + norm zero ----
// lane l handles 4 consecutive cols [4l, 4l+4): float4 loads (16B, aligned since 196%4==0),
// uint2 stores per plane. Cols >= 196 are zero-padded.
__global__ __launch_bounds__(256) void xcast_kernel(const float* __restrict__ x,
        unsigned short* __restrict__ xs, float* __restrict__ means, float* __restrict__ norm) {
    int b = blockIdx.y;
    int r0 = blockIdx.x * 64;
    int w = threadIdx.x >> 6, lane = threadIdx.x & 63;
    const float* xb = x + (size_t)b * CDIM * MDIM;
    unsigned short* xh = xs + (size_t)b * SLOT_STRIDE;
    unsigned short* xl = xh + PLANE;
    if (threadIdx.x == 0 && blockIdx.x == 0) norm[b] = 0.f;
    int c0 = lane * 4;
    for (int k = 0; k < 16; k++) {
        int row = r0 + w * 16 + k;
        float4 v = (c0 + 4 <= MDIM) ? *(const float4*)&xb[(size_t)row * MDIM + c0]
                                    : make_float4(0.f, 0.f, 0.f, 0.f);
        float s = v.x + v.y + v.z + v.w;
#pragma unroll
        for (int off = 32; off > 0; off >>= 1) s += __shfl_down(s, off);
        if (lane == 0) means[b * CDIM + row] = s * (1.f / MDIM);
        unsigned short hs[4], ls[4];
        float vv[4] = {v.x, v.y, v.z, v.w};
#pragma unroll
        for (int j = 0; j < 4; j++) {
            unsigned short h = f2bf(vv[j]);
            hs[j] = h;
            ls[j] = f2bf(vv[j] - bf2f(h));
        }
        *(uint2*)&xh[(size_t)row * CDIM + c0] = *(uint2*)hs;
        *(uint2*)&xl[(size_t)row * CDIM + c0] = *(uint2*)ls;
    }
}

// ---------- Ahat = A/norm (in place), Z0 = 1.5 I - 0.5 Ahat ----------
__global__ void prep_kernel(unsigned short* __restrict__ A, unsigned short* __restrict__ Z,
                            const float* __restrict__ norm, int bc) {
    int idx = blockIdx.x * 256 + threadIdx.x;   // one thread per 8 elements
    int total = bc * (MATN / 8);
    if (idx >= total) return;
    int b = idx >> 13;                          // MATN/8 = 8192
    int e0 = (idx & 8191) << 3;
    int r = e0 >> 8, c0 = e0 & 255;
    unsigned short* Ahi = A + (size_t)b * SLOT_STRIDE;
    unsigned short* Alo = Ahi + PLANE;
    unsigned short* Zhi = Z + (size_t)b * SLOT_STRIDE;
    unsigned short* Zlo = Zhi + PLANE;
    float inv = 1.f / norm[b];
    unsigned short h[8], l[8], ah[8], al[8], zh[8], zl[8];
    *(uint4*)h = *(const uint4*)&Ahi[e0];
    *(uint4*)l = *(const uint4*)&Alo[e0];
#pragma unroll
    for (int k = 0; k < 8; k++) {
        float val = (bf2f(h[k]) + bf2f(l[k])) * inv;        // Ahat element
        unsigned short hh = f2bf(val);
        ah[k] = hh; al[k] = f2bf(val - bf2f(hh));
        float z = ((r == c0 + k) ? 1.5f : 0.f) - 0.5f * val;
        unsigned short zz = f2bf(z);
        zh[k] = zz; zl[k] = f2bf(z - bf2f(zz));
    }
    *(uint4*)&Ahi[e0] = *(uint4*)ah;
    *(uint4*)&Alo[e0] = *(uint4*)al;
    *(uint4*)&Zhi[e0] = *(uint4*)zh;
    *(uint4*)&Zlo[e0] = *(uint4*)zl;
}

// ---------- unified batched MFMA GEMM on hi/lo bf16 planes (full 16-tile output) ----------
// kind 0: D = A@B/M - mu mu^T (covariance), fused trace->atomicAdd(norm)
// kind 1: D = alpha*A@B + beta*C
// kind 2: fc epilogue: out[b0+b] += fc(triu(sqrt(norm)*(alpha*A@B + beta*C)))  (no D write)
// 1-D grid of 16*bc blocks, XCD-pinned (bc%8==0): blocks round-robin XCDs by lin%8, so
// XCD x walks batches [x*bc/8, (x+1)*bc/8) in order; ~4 concurrent batches x 1 MiB fit
// its 4 MiB L2 regardless of bc. B-operand read row-major relying on symmetry.
__global__ __launch_bounds__(256) void bgemm_kernel(
        const unsigned short* __restrict__ Abase, const unsigned short* __restrict__ Bbase,
        const unsigned short* __restrict__ Cbase, unsigned short* __restrict__ Dbase,
        float alpha, float beta, int kind, float* __restrict__ norm,
        const float* __restrict__ means,
        const float* __restrict__ fcw, float* __restrict__ out, int b0, int bc) {
    __shared__ __align__(16) char lds[2][4][8192];   // [dbuf][Ah,Al,Bh,Bl][64 rows x 8 chunks x 16B]
    int tid = threadIdx.x;
    int lin = blockIdx.x;
    int b, tile;
    if ((bc & 7) == 0) {            // XCD-pinned mapping
        int xcd = lin & 7;
        int i = lin >> 3;
        b = xcd * (bc >> 3) + (i >> 4);
        tile = i & 15;
    } else { b = lin >> 4; tile = lin & 15; }
    int r0 = (tile >> 2) * 64, c0 = (tile & 3) * 64;

    const unsigned short* Ab = Abase + (size_t)b * SLOT_STRIDE;
    const unsigned short* Bb = Bbase + (size_t)b * SLOT_STRIDE;
    const unsigned short* srcs[4] = { Ab + (size_t)r0 * CDIM, Ab + PLANE + (size_t)r0 * CDIM,
                                      Bb + (size_t)c0 * CDIM, Bb + PLANE + (size_t)c0 * CDIM };

    int w = tid >> 6, lane = tid & 63;
    int wr = w >> 1, wc = w & 1;
    int fr = lane & 15, kq = lane >> 4;

    f32x4 acc[2][2];
#pragma unroll
    for (int i = 0; i < 2; i++)
#pragma unroll
        for (int j = 0; j < 2; j++) acc[i][j] = (f32x4){0.f, 0.f, 0.f, 0.f};

    // LDS chunk (m, c) holds logical k-window (c ^ (m&7)); dest is wave-linear so
    // global_load_lds works; the swizzle lives in the per-lane GLOBAL address.
#define STAGE(buf, k0) do {                                                              \
    _Pragma("unroll")                                                                    \
    for (int p = 0; p < 4; p++) {                                                        \
        _Pragma("unroll")                                                                \
        for (int s = 0; s < 2; s++) {                                                    \
            int cid = s * 256 + tid;                                                     \
            int m = cid >> 3;                                                            \
            int kg = (cid & 7) ^ (m & 7);                                                \
            const unsigned short* g = srcs[p] + (size_t)m * CDIM + (k0) + kg * 8;        \
            void* lp = (void*)&lds[buf][p][(s * 256 + (tid & ~63)) * 16];                \
            __builtin_amdgcn_global_load_lds(                                            \
                (const __attribute__((address_space(1))) void*)g,                        \
                (__attribute__((address_space(3))) void*)(unsigned int)(unsigned long long)lp, \
                16, 0, 0);                                                               \
        }                                                                                \
    } } while (0)

    STAGE(0, 0);
    __syncthreads();

    int cur = 0;
    for (int k0 = 0; k0 < CDIM; k0 += 64) {
        if (k0 + 64 < CDIM) STAGE(cur ^ 1, k0 + 64);
#pragma unroll
        for (int h = 0; h < 2; h++) {
            bf16x8 fAh[2], fAl[2], fBh[2], fBl[2];
#pragma unroll
            for (int i = 0; i < 2; i++) {
                int mL = wr * 32 + i * 16 + fr;
                int ca = ((h * 4 + kq) ^ (mL & 7));
                fAh[i] = *(const bf16x8*)&lds[cur][0][(mL * 8 + ca) * 16];
                fAl[i] = *(const bf16x8*)&lds[cur][1][(mL * 8 + ca) * 16];
                int nL = wc * 32 + i * 16 + fr;
                int cb = ((h * 4 + kq) ^ (nL & 7));
                fBh[i] = *(const bf16x8*)&lds[cur][2][(nL * 8 + cb) * 16];
                fBl[i] = *(const bf16x8*)&lds[cur][3][(nL * 8 + cb) * 16];
            }
#pragma unroll
            for (int i = 0; i < 2; i++)
#pragma unroll
                for (int j = 0; j < 2; j++) {
                    acc[i][j] = __builtin_amdgcn_mfma_f32_16x16x32_bf16(fAh[i], fBh[j], acc[i][j], 0, 0, 0);
                    acc[i][j] = __builtin_amdgcn_mfma_f32_16x16x32_bf16(fAh[i], fBl[j], acc[i][j], 0, 0, 0);
                    acc[i][j] = __builtin_amdgcn_mfma_f32_16x16x32_bf16(fAl[i], fBh[j], acc[i][j], 0, 0, 0);
                }
        }
        __syncthreads();
        cur ^= 1;
    }

    const unsigned short* Chi = Cbase ? Cbase + (size_t)b * SLOT_STRIDE : nullptr;
    const unsigned short* Clo = Chi ? Chi + PLANE : nullptr;

    if (kind == 2) {
        float s = sqrtf(norm[b]);
        float s0 = 0.f, s1 = 0.f;
#pragma unroll
        for (int i = 0; i < 2; i++)
#pragma unroll
            for (int j = 0; j < 2; j++)
#pragma unroll
                for (int rr = 0; rr < 4; rr++) {
                    int row = r0 + wr * 32 + i * 16 + kq * 4 + rr;
                    int col = c0 + wc * 32 + j * 16 + fr;
                    float v = alpha * acc[i][j][rr];
                    if (Chi) v += beta * (bf2f(Chi[row * CDIM + col]) + bf2f(Clo[row * CDIM + col]));
                    v *= s;
                    if (col >= row) {
                        int t = row * CDIM - (row * (row - 1)) / 2 + (col - row);
                        s0 = fmaf(v, fcw[t], s0);
                        s1 = fmaf(v, fcw[DTRI + t], s1);
                    }
                }
#pragma unroll
        for (int off = 32; off > 0; off >>= 1) { s0 += __shfl_down(s0, off); s1 += __shfl_down(s1, off); }
        __syncthreads();
        float* red = (float*)&lds[0][0][0];
        if (lane == 0) { red[w * 2] = s0; red[w * 2 + 1] = s1; }
        __syncthreads();
        if (tid == 0) {
            atomicAdd(&out[(size_t)(b0 + b) * 2 + 0], red[0] + red[2] + red[4] + red[6]);
            atomicAdd(&out[(size_t)(b0 + b) * 2 + 1], red[1] + red[3] + red[5] + red[7]);
        }
        return;
    }

    unsigned short* Dhi = Dbase + (size_t)b * SLOT_STRIDE;
    unsigned short* Dlo = Dhi + PLANE;

    if (kind == 0) {
        const float* mub = means + b * CDIM;
        float tsum = 0.f;
#pragma unroll
        for (int i = 0; i < 2; i++)
#pragma unroll
            for (int j = 0; j < 2; j++)
#pragma unroll
                for (int rr = 0; rr < 4; rr++) {
                    int row = r0 + wr * 32 + i * 16 + kq * 4 + rr;
                    int col = c0 + wc * 32 + j * 16 + fr;
                    float v = acc[i][j][rr] * (1.f / MDIM) - mub[row] * mub[col];
                    if (row == col) tsum += v;
                    unsigned short hh = f2bf(v);
                    Dhi[row * CDIM + col] = hh;
                    Dlo[row * CDIM + col] = f2bf(v - bf2f(hh));
                }
        if (r0 == c0 && wr == wc) {              // fused trace: wave-reduce, 1 atomic/wave
#pragma unroll
            for (int off = 32; off > 0; off >>= 1) tsum += __shfl_down(tsum, off);
            if (lane == 0) atomicAdd(&norm[b], tsum);
        }
    } else {
#pragma unroll
        for (int i = 0; i < 2; i++)
#pragma unroll
            for (int j = 0; j < 2; j++)
#pragma unroll
                for (int rr = 0; rr < 4; rr++) {
                    int row = r0 + wr * 32 + i * 16 + kq * 4 + rr;
                    int col = c0 + wc * 32 + j * 16 + fr;
                    float v = alpha * acc[i][j][rr];
                    if (Chi) v += beta * (bf2f(Chi[row * CDIM + col]) + bf2f(Clo[row * CDIM + col]));
                    unsigned short hh = f2bf(v);
                    Dhi[row * CDIM + col] = hh;
                    Dlo[row * CDIM + col] = f2bf(v - bf2f(hh));
                }
    }
#undef STAGE
}

// ---------- out init with bias ----------
__global__ void init_out(float* __restrict__ out, const float* __restrict__ bias, int n) {
    int i = blockIdx.x * 256 + threadIdx.x;
    if (i < n) out[i] = bias[i & 1];
}

extern "C" void kernel_launch(void* const* d_in, const int* in_sizes, int n_in,
                              void* d_out, int out_size, void* d_ws, size_t ws_size,
                              hipStream_t stream) {
    const float* x    = (const float*)d_in[0];
    const float* fc_w = (const float*)d_in[1];
    const float* fc_b = (const float*)d_in[2];
    float* out = (float*)d_out;
    int B = in_sizes[0] / (CDIM * MDIM);

    size_t per_b = (size_t)4 * SLOT_STRIDE * sizeof(unsigned short)
                 + (size_t)CDIM * sizeof(float) + sizeof(float);
    int Bcmax = (int)(ws_size / per_b);
    if (Bcmax < 1) Bcmax = 1;
    if (Bcmax > B) Bcmax = B;
    // Balanced chunks, as large as ws allows (256 MiB -> Bc=128, 2 chunks).
    // Dispatch count is the dominant overhead at this problem size; L2 residency
    // is preserved by the XCD-pinned mapping regardless of Bc (only ~4 batches
    // are concurrently resident per XCD).
    int nch = (B + Bcmax - 1) / Bcmax;
    int Bc = (B + nch - 1) / nch;
    if (Bc >= 8) Bc &= ~7;

    char* p = (char*)d_ws;
    unsigned short* slot[4];
    for (int i = 0; i < 4; i++) { slot[i] = (unsigned short*)p; p += (size_t)Bc * SLOT_STRIDE * sizeof(unsigned short); }
    float* means = (float*)p; p += (size_t)Bc * CDIM * sizeof(float);
    float* norm  = (float*)p;

    init_out<<<(out_size + 255) / 256, 256, 0, stream>>>(out, fc_b, out_size);

    for (int b0 = 0; b0 < B; b0 += Bc) {
        int bc = (Bc < B - b0) ? Bc : (B - b0);
        const float* xb = x + (size_t)b0 * CDIM * MDIM;

        unsigned short* A  = slot[0];
        unsigned short* z  = slot[1];
        unsigned short* t1 = slot[2];
        unsigned short* t2 = slot[3];

        // x -> bf16 planes in t2 (dead until GEMM2), + means + norm=0
        xcast_kernel<<<dim3(4, bc), 256, 0, stream>>>(xb, t2, means, norm);
        // covariance via MFMA (A=B=x planes), fused trace
        bgemm_kernel<<<16 * bc, 256, 0, stream>>>(t2, t2, nullptr, A, 0.f, 0.f, 0, norm, means, nullptr, nullptr, b0, bc);
        // Ahat in place + Z0
        prep_kernel<<<bc * 32, 256, 0, stream>>>(A, z, norm, bc);

        int g = 16 * bc;
        for (int it = 0; it < 3; it++) {
            bgemm_kernel<<<g, 256, 0, stream>>>(A,  z,  nullptr, t1, 1.f,  0.f, 1, norm, means, nullptr, nullptr, b0, bc); // t1 = Ahat@z
            bgemm_kernel<<<g, 256, 0, stream>>>(z,  t1, nullptr, t2, 1.f,  0.f, 1, norm, means, nullptr, nullptr, b0, bc); // t2 = z@t1
            bgemm_kernel<<<g, 256, 0, stream>>>(t2, z,  z,       t1, -0.5f, 1.5f, 1, norm, means, nullptr, nullptr, b0, bc); // z' = 1.5z-0.5 t2@z
            unsigned short* tmp = z; z = t1; t1 = tmp;
        }
        bgemm_kernel<<<g, 256, 0, stream>>>(A, z,  nullptr, t1, 1.f,  0.f, 1, norm, means, nullptr, nullptr, b0, bc);      // Y3 = Ahat@z
        bgemm_kernel<<<g, 256, 0, stream>>>(z, t1, nullptr, t2, 1.f,  0.f, 1, norm, means, nullptr, nullptr, b0, bc);      // P  = z@Y3
        bgemm_kernel<<<g, 256, 0, stream>>>(t1, t2, t1, nullptr, -0.5f, 1.5f, 2, norm, means, fc_w, out, b0, bc);          // fc epilogue
    }
}

// Round 8
// 468.719 us; speedup vs baseline: 2.4518x; 1.6964x over previous
//
#include <hip/hip_runtime.h>
#include <hip/hip_bf16.h>

#define CDIM 256
#define MDIM 196
#define MATN (CDIM*CDIM)          // 65536
#define DTRI (CDIM*(CDIM+1)/2)    // 32896
#define SLOT 65536                // f16 elements per matrix slot (single plane, 128 KB)

typedef _Float16 f16;
typedef __attribute__((ext_vector_type(8))) _Float16 f16x8;
typedef __attribute__((ext_vector_type(4))) float f32x4;

// ---------- x -> f16 plane (K padded 196->256 with zeros) + row means + norm zero ----------
// lane l handles 4 consecutive cols: float4 load, 4xf16 (8B) store.
__global__ __launch_bounds__(256) void xcast_kernel(const float* __restrict__ x,
        f16* __restrict__ xs, float* __restrict__ means, float* __restrict__ norm) {
    int b = blockIdx.y;
    int r0 = blockIdx.x * 64;
    int w = threadIdx.x >> 6, lane = threadIdx.x & 63;
    const float* xb = x + (size_t)b * CDIM * MDIM;
    f16* xh = xs + (size_t)b * SLOT;
    if (threadIdx.x == 0 && blockIdx.x == 0) norm[b] = 0.f;
    int c0 = lane * 4;
    for (int k = 0; k < 16; k++) {
        int row = r0 + w * 16 + k;
        float4 v = (c0 + 4 <= MDIM) ? *(const float4*)&xb[(size_t)row * MDIM + c0]
                                    : make_float4(0.f, 0.f, 0.f, 0.f);
        float s = v.x + v.y + v.z + v.w;
#pragma unroll
        for (int off = 32; off > 0; off >>= 1) s += __shfl_down(s, off);
        if (lane == 0) means[b * CDIM + row] = s * (1.f / MDIM);
        f16 hs[4] = {(f16)v.x, (f16)v.y, (f16)v.z, (f16)v.w};
        *(uint2*)&xh[(size_t)row * CDIM + c0] = *(uint2*)hs;
    }
}

// ---------- Ahat = A/norm (in place), Z0 = 1.5 I - 0.5 Ahat ----------
__global__ void prep_kernel(f16* __restrict__ A, f16* __restrict__ Z,
                            const float* __restrict__ norm, int bc) {
    int idx = blockIdx.x * 256 + threadIdx.x;   // one thread per 8 elements
    int total = bc * (MATN / 8);
    if (idx >= total) return;
    int b = idx >> 13;                          // MATN/8 = 8192
    int e0 = (idx & 8191) << 3;
    int r = e0 >> 8, c0 = e0 & 255;
    f16* Ab = A + (size_t)b * SLOT;
    f16* Zb = Z + (size_t)b * SLOT;
    float inv = 1.f / norm[b];
    f16 h[8], ah[8], zh[8];
    *(uint4*)h = *(const uint4*)&Ab[e0];
#pragma unroll
    for (int k = 0; k < 8; k++) {
        float val = (float)h[k] * inv;          // Ahat element
        ah[k] = (f16)val;
        zh[k] = (f16)(((r == c0 + k) ? 1.5f : 0.f) - 0.5f * val);
    }
    *(uint4*)&Ab[e0] = *(uint4*)ah;
    *(uint4*)&Zb[e0] = *(uint4*)zh;
}

// ---------- batched MFMA GEMM, f16 single plane, 128x128 tile, 4 waves x (64x64) ----------
// kind 0: D = A@B/M - mu mu^T (covariance), fused trace->atomicAdd(norm)
// kind 1: D = alpha*A@B + beta*C
// kind 2: fc epilogue: out[b0+b] += fc(triu(sqrt(norm)*(alpha*A@B + beta*C)))  (no D write)
// Grid 4*bc, XCD-pinned (bc%8==0): XCD x walks its batches in order, 4 tiles each;
// concurrent working set per XCD ~ (A+B+D) x ~8 batches ~= 3-4 MiB ~= its L2.
// B-operand read row-major relying on symmetry of all operands.
__global__ __launch_bounds__(256) void bgemm_kernel(
        const f16* __restrict__ Abase, const f16* __restrict__ Bbase,
        const f16* __restrict__ Cbase, f16* __restrict__ Dbase,
        float alpha, float beta, int kind, float* __restrict__ norm,
        const float* __restrict__ means,
        const float* __restrict__ fcw, float* __restrict__ out, int b0, int bc) {
    __shared__ __align__(16) char lds[2][2][16384];  // [dbuf][A,B][128 rows x 8 chunks x 16B]
    int tid = threadIdx.x;
    int lin = blockIdx.x;
    int b, tile;
    if ((bc & 7) == 0) {            // XCD-pinned mapping
        int xcd = lin & 7;
        int i = lin >> 3;
        b = xcd * (bc >> 3) + (i >> 2);
        tile = i & 3;
    } else { b = lin >> 2; tile = lin & 3; }
    int r0 = (tile >> 1) * 128, c0 = (tile & 1) * 128;

    const f16* Ab = Abase + (size_t)b * SLOT;
    const f16* Bb = Bbase + (size_t)b * SLOT;
    const f16* srcs[2] = { Ab + (size_t)r0 * CDIM, Bb + (size_t)c0 * CDIM };

    int w = tid >> 6, lane = tid & 63;
    int wr = w >> 1, wc = w & 1;                 // wave covers rows wr*64.., cols wc*64..
    int fr = lane & 15, kq = lane >> 4;

    f32x4 acc[4][4];
#pragma unroll
    for (int i = 0; i < 4; i++)
#pragma unroll
        for (int j = 0; j < 4; j++) acc[i][j] = (f32x4){0.f, 0.f, 0.f, 0.f};

    // LDS chunk (m, c) holds logical k-window (c ^ (m&7)); dest is wave-linear so
    // global_load_lds works; the swizzle lives in the per-lane GLOBAL address.
#define STAGE(buf, k0) do {                                                              \
    _Pragma("unroll")                                                                    \
    for (int p = 0; p < 2; p++) {                                                        \
        _Pragma("unroll")                                                                \
        for (int s = 0; s < 4; s++) {                                                    \
            int cid = s * 256 + tid;                                                     \
            int m = cid >> 3;                                                            \
            int kg = (cid & 7) ^ (m & 7);                                                \
            const f16* g = srcs[p] + (size_t)m * CDIM + (k0) + kg * 8;                   \
            void* lp = (void*)&lds[buf][p][(s * 256 + (tid & ~63)) * 16];                \
            __builtin_amdgcn_global_load_lds(                                            \
                (const __attribute__((address_space(1))) void*)g,                        \
                (__attribute__((address_space(3))) void*)(unsigned int)(unsigned long long)lp, \
                16, 0, 0);                                                               \
        }                                                                                \
    } } while (0)

    STAGE(0, 0);
    __syncthreads();

    int cur = 0;
    for (int k0 = 0; k0 < CDIM; k0 += 64) {
        if (k0 + 64 < CDIM) STAGE(cur ^ 1, k0 + 64);
#pragma unroll
        for (int h = 0; h < 2; h++) {
            f16x8 fA[4], fB[4];
#pragma unroll
            for (int i = 0; i < 4; i++) {
                int mL = wr * 64 + i * 16 + fr;
                int ca = ((h * 4 + kq) ^ (mL & 7));
                fA[i] = *(const f16x8*)&lds[cur][0][(mL * 8 + ca) * 16];
                int nL = wc * 64 + i * 16 + fr;
                int cb = ((h * 4 + kq) ^ (nL & 7));
                fB[i] = *(const f16x8*)&lds[cur][1][(nL * 8 + cb) * 16];
            }
#pragma unroll
            for (int i = 0; i < 4; i++)
#pragma unroll
                for (int j = 0; j < 4; j++)
                    acc[i][j] = __builtin_amdgcn_mfma_f32_16x16x32_f16(fA[i], fB[j], acc[i][j], 0, 0, 0);
        }
        __syncthreads();
        cur ^= 1;
    }

    const f16* Cb = Cbase ? Cbase + (size_t)b * SLOT : nullptr;

    if (kind == 2) {
        float s = sqrtf(norm[b]);
        float s0 = 0.f, s1 = 0.f;
#pragma unroll
        for (int i = 0; i < 4; i++)
#pragma unroll
            for (int j = 0; j < 4; j++)
#pragma unroll
                for (int rr = 0; rr < 4; rr++) {
                    int row = r0 + wr * 64 + i * 16 + kq * 4 + rr;
                    int col = c0 + wc * 64 + j * 16 + fr;
                    if (col >= row) {
                        float v = alpha * acc[i][j][rr];
                        if (Cb) v += beta * (float)Cb[row * CDIM + col];
                        v *= s;
                        int t = row * CDIM - (row * (row - 1)) / 2 + (col - row);
                        s0 = fmaf(v, fcw[t], s0);
                        s1 = fmaf(v, fcw[DTRI + t], s1);
                    }
                }
#pragma unroll
        for (int off = 32; off > 0; off >>= 1) { s0 += __shfl_down(s0, off); s1 += __shfl_down(s1, off); }
        __syncthreads();
        float* red = (float*)&lds[0][0][0];
        if (lane == 0) { red[w * 2] = s0; red[w * 2 + 1] = s1; }
        __syncthreads();
        if (tid == 0) {
            atomicAdd(&out[(size_t)(b0 + b) * 2 + 0], red[0] + red[2] + red[4] + red[6]);
            atomicAdd(&out[(size_t)(b0 + b) * 2 + 1], red[1] + red[3] + red[5] + red[7]);
        }
        return;
    }

    f16* Db = Dbase + (size_t)b * SLOT;

    if (kind == 0) {
        const float* mub = means + b * CDIM;
        float tsum = 0.f;
#pragma unroll
        for (int i = 0; i < 4; i++)
#pragma unroll
            for (int j = 0; j < 4; j++)
#pragma unroll
                for (int rr = 0; rr < 4; rr++) {
                    int row = r0 + wr * 64 + i * 16 + kq * 4 + rr;
                    int col = c0 + wc * 64 + j * 16 + fr;
                    float v = acc[i][j][rr] * (1.f / MDIM) - mub[row] * mub[col];
                    if (row == col) tsum += v;
                    Db[row * CDIM + col] = (f16)v;
                }
        if (r0 == c0 && wr == wc) {              // fused trace: wave-reduce, 1 atomic/wave
#pragma unroll
            for (int off = 32; off > 0; off >>= 1) tsum += __shfl_down(tsum, off);
            if (lane == 0) atomicAdd(&norm[b], tsum);
        }
    } else {
#pragma unroll
        for (int i = 0; i < 4; i++)
#pragma unroll
            for (int j = 0; j < 4; j++)
#pragma unroll
                for (int rr = 0; rr < 4; rr++) {
                    int row = r0 + wr * 64 + i * 16 + kq * 4 + rr;
                    int col = c0 + wc * 64 + j * 16 + fr;
                    float v = alpha * acc[i][j][rr];
                    if (Cb) v += beta * (float)Cb[row * CDIM + col];
                    Db[row * CDIM + col] = (f16)v;
                }
    }
#undef STAGE
}

// ---------- out init with bias ----------
__global__ void init_out(float* __restrict__ out, const float* __restrict__ bias, int n) {
    int i = blockIdx.x * 256 + threadIdx.x;
    if (i < n) out[i] = bias[i & 1];
}

extern "C" void kernel_launch(void* const* d_in, const int* in_sizes, int n_in,
                              void* d_out, int out_size, void* d_ws, size_t ws_size,
                              hipStream_t stream) {
    const float* x    = (const float*)d_in[0];
    const float* fc_w = (const float*)d_in[1];
    const float* fc_b = (const float*)d_in[2];
    float* out = (float*)d_out;
    int B = in_sizes[0] / (CDIM * MDIM);

    size_t per_b = (size_t)4 * SLOT * sizeof(f16)
                 + (size_t)CDIM * sizeof(float) + sizeof(float);
    int Bcmax = (int)(ws_size / per_b);
    if (Bcmax < 1) Bcmax = 1;
    if (Bcmax > B) Bcmax = B;
    // f16 single-plane slots (512 KB/batch): 256 MiB ws -> single chunk at B=256.
    int nch = (B + Bcmax - 1) / Bcmax;
    int Bc = (B + nch - 1) / nch;
    if (Bc >= 8) Bc &= ~7;

    char* p = (char*)d_ws;
    f16* slot[4];
    for (int i = 0; i < 4; i++) { slot[i] = (f16*)p; p += (size_t)Bc * SLOT * sizeof(f16); }
    float* means = (float*)p; p += (size_t)Bc * CDIM * sizeof(float);
    float* norm  = (float*)p;

    init_out<<<(out_size + 255) / 256, 256, 0, stream>>>(out, fc_b, out_size);

    for (int b0 = 0; b0 < B; b0 += Bc) {
        int bc = (Bc < B - b0) ? Bc : (B - b0);
        const float* xb = x + (size_t)b0 * CDIM * MDIM;

        f16* A  = slot[0];
        f16* z  = slot[1];
        f16* t1 = slot[2];
        f16* t2 = slot[3];

        // x -> f16 plane in t2 (dead until GEMM2), + means + norm=0
        xcast_kernel<<<dim3(4, bc), 256, 0, stream>>>(xb, t2, means, norm);
        // covariance via MFMA (A=B=x plane), fused trace
        bgemm_kernel<<<4 * bc, 256, 0, stream>>>(t2, t2, nullptr, A, 0.f, 0.f, 0, norm, means, nullptr, nullptr, b0, bc);
        // Ahat in place + Z0
        prep_kernel<<<bc * 32, 256, 0, stream>>>(A, z, norm, bc);

        int g = 4 * bc;
        for (int it = 0; it < 3; it++) {
            bgemm_kernel<<<g, 256, 0, stream>>>(A,  z,  nullptr, t1, 1.f,  0.f, 1, norm, means, nullptr, nullptr, b0, bc); // t1 = Ahat@z
            bgemm_kernel<<<g, 256, 0, stream>>>(z,  t1, nullptr, t2, 1.f,  0.f, 1, norm, means, nullptr, nullptr, b0, bc); // t2 = z@t1
            bgemm_kernel<<<g, 256, 0, stream>>>(t2, z,  z,       t1, -0.5f, 1.5f, 1, norm, means, nullptr, nullptr, b0, bc); // z' = 1.5z-0.5 t2@z
            f16* tmp = z; z = t1; t1 = tmp;
        }
        bgemm_kernel<<<g, 256, 0, stream>>>(A, z,  nullptr, t1, 1.f,  0.f, 1, norm, means, nullptr, nullptr, b0, bc);      // Y3 = Ahat@z
        bgemm_kernel<<<g, 256, 0, stream>>>(z, t1, nullptr, t2, 1.f,  0.f, 1, norm, means, nullptr, nullptr, b0, bc);      // P  = z@Y3
        bgemm_kernel<<<g, 256, 0, stream>>>(t1, t2, t1, nullptr, -0.5f, 1.5f, 2, norm, means, fc_w, out, b0, bc);          // fc epilogue
    }
}